// Round 1
// baseline (1236.410 us; speedup 1.0000x reference)
//
#include <hip/hip_runtime.h>

// RoIAlignRotated: features (B=2, C=256, H=200, W=200) f32, rois (N, 6) f32
// rois row: [batch_idx, cx, cy, w, h, theta]; out (N, C, 7, 7) f32.
// Block = one roi; prologue builds the 196-sample weight/index table in LDS
// (channel-independent), main loop strides the 12544 outputs with coalesced
// writes and LDS-driven gathers.

#define C_ 256
#define H_ 200
#define W_ 200
#define OUTHW 7
#define GRID_S 14          // OUTHW * sampling_ratio(2)
#define NSAMP 196          // 14*14
#define ELEMS (C_ * OUTHW * OUTHW)  // 12544 outputs per roi

__global__ __launch_bounds__(256) void roi_align_rotated_kernel(
    const float* __restrict__ feat,
    const float* __restrict__ rois,
    float* __restrict__ out)
{
    const int n = blockIdx.x;
    const int t = threadIdx.x;

    __shared__ float s_w[4][NSAMP];   // bilinear weights (inside & 0.25 folded in)
    __shared__ int   s_idx[4][NSAMP]; // flat y*W+x offsets within one channel plane
    __shared__ int   s_b;             // batch index

    // --- per-roi parameters (broadcast reads, cheap) ---
    const float spatial_scale = 0.25f;
    const float r_b  = rois[n * 6 + 0];
    const float cx   = rois[n * 6 + 1] * spatial_scale;
    const float cy   = rois[n * 6 + 2] * spatial_scale;
    const float rw   = fmaxf(rois[n * 6 + 3] * spatial_scale, 1.0f);
    const float rh   = fmaxf(rois[n * 6 + 4] * spatial_scale, 1.0f);
    const float th   = rois[n * 6 + 5];

    if (t == 0) s_b = (int)r_b;

    // --- sample table: one thread per sample point ---
    if (t < NSAMP) {
        const float cs = __cosf(th) ;
        const float sn = __sinf(th);
        // NOTE: use precise cos/sin — threshold is loose but keep f32-exact path
        const float cosv = cosf(th), sinv = sinf(th);
        (void)cs; (void)sn;

        const float bin_h = rh * (1.0f / OUTHW);
        const float bin_w = rw * (1.0f / OUTHW);
        const int row = t / GRID_S;   // index into yy (sy)
        const int col = t % GRID_S;   // index into xx (sx)

        // sy = (row + 0.5)/2 ; yy = -rh/2 + sy*bin_h  (g = 2)
        const float yy = -rh * 0.5f + ((float)row + 0.5f) * 0.5f * bin_h;
        const float xx = -rw * 0.5f + ((float)col + 0.5f) * 0.5f * bin_w;

        const float y = yy * cosv - xx * sinv + cy;
        const float x = yy * sinv + xx * cosv + cx;

        const bool inside = (y >= -1.0f) && (y <= (float)H_) &&
                            (x >= -1.0f) && (x <= (float)W_);

        const float yc = fmaxf(y, 0.0f);
        const float xc = fmaxf(x, 0.0f);
        const float fy = floorf(yc);
        const float fx = floorf(xc);
        int yl = min((int)fy, H_ - 1);
        int xl = min((int)fx, W_ - 1);
        const int yh = min(yl + 1, H_ - 1);
        const int xh = min(xl + 1, W_ - 1);
        const float ly = (fy >= (float)(H_ - 1)) ? 0.0f : (yc - fy);
        const float lx = (fx >= (float)(W_ - 1)) ? 0.0f : (xc - fx);
        const float hy = 1.0f - ly;
        const float hx = 1.0f - lx;

        const float m = inside ? 0.25f : 0.0f;  // fold inside-mask + 2x2 mean
        s_w[0][t] = hy * hx * m;
        s_w[1][t] = hy * lx * m;
        s_w[2][t] = ly * hx * m;
        s_w[3][t] = ly * lx * m;
        s_idx[0][t] = yl * W_ + xl;
        s_idx[1][t] = yl * W_ + xh;
        s_idx[2][t] = yh * W_ + xl;
        s_idx[3][t] = yh * W_ + xh;
    }
    __syncthreads();

    const float* __restrict__ fb = feat + (size_t)s_b * (size_t)(C_ * H_ * W_);
    float* __restrict__ ob = out + (size_t)n * (size_t)ELEMS;

    // 12544 outputs / 256 threads = 49 iterations, coalesced writes
    for (int e = t; e < ELEMS; e += 256) {
        const int c   = e / 49;
        const int bin = e - c * 49;
        const int oy  = bin / 7;
        const int ox  = bin - oy * 7;
        const float* __restrict__ fc = fb + c * (H_ * W_);

        float acc = 0.0f;
        #pragma unroll
        for (int j = 0; j < 2; ++j) {
            #pragma unroll
            for (int i = 0; i < 2; ++i) {
                const int s = (oy * 2 + j) * GRID_S + (ox * 2 + i);
                acc += s_w[0][s] * fc[s_idx[0][s]];
                acc += s_w[1][s] * fc[s_idx[1][s]];
                acc += s_w[2][s] * fc[s_idx[2][s]];
                acc += s_w[3][s] * fc[s_idx[3][s]];
            }
        }
        ob[e] = acc;
    }
}

extern "C" void kernel_launch(void* const* d_in, const int* in_sizes, int n_in,
                              void* d_out, int out_size, void* d_ws, size_t ws_size,
                              hipStream_t stream) {
    const float* feat = (const float*)d_in[0];
    const float* rois = (const float*)d_in[1];
    float* out = (float*)d_out;
    const int N = in_sizes[1] / 6;  // 1000
    roi_align_rotated_kernel<<<N, 256, 0, stream>>>(feat, rois, out);
}

// Round 2
// 345.746 us; speedup vs baseline: 3.5761x; 3.5761x over previous
//
#include <hip/hip_runtime.h>

// RoIAlignRotated on MI355X.
// R1 strategy: features (B,C,H,W) are transposed once into d_ws as NHWC so
// every bilinear corner is a contiguous 1 KB run of 256 channels. Main kernel
// maps lanes to channels (float4 each) -> all gathers fully coalesced.
// Per-roi 196-sample weight/index table built once in LDS (channel-indep).

#define B_ 2
#define C_ 256
#define H_ 200
#define W_ 200
#define OUTHW 7
#define GRID_S 14          // OUTHW * sampling_ratio(2)
#define NSAMP 196          // 14*14
#define ELEMS (C_ * OUTHW * OUTHW)  // 12544 outputs per roi

// ---------- NCHW -> NHWC transpose (one-shot, ~330 MB traffic) ----------
__global__ __launch_bounds__(256) void transpose_kernel(
    const float* __restrict__ feat, float* __restrict__ featT)
{
    const int c  = threadIdx.x;          // 256 channels
    const int x0 = blockIdx.x * 16;
    const int y  = blockIdx.y;
    const int b  = blockIdx.z;
    const int nx = (x0 + 16 <= W_) ? 16 : (W_ - x0);

    const float4* s4 = (const float4*)(feat +
        (((size_t)(b * C_ + c) * H_ + y) * W_ + x0));
    float v[16];
    #pragma unroll
    for (int q = 0; q < 4; ++q) {
        if (q * 4 < nx) {
            float4 t4 = s4[q];
            v[q*4+0] = t4.x; v[q*4+1] = t4.y; v[q*4+2] = t4.z; v[q*4+3] = t4.w;
        }
    }
    float* dst = featT + ((size_t)(b * H_ + y) * W_ + x0) * C_ + c;
    for (int k = 0; k < nx; ++k) dst[(size_t)k * C_] = v[k];  // 1 KB coalesced per k
}

// ---------- sample-table build (shared by both main kernels) ----------
__device__ __forceinline__ void build_table(
    const float* __restrict__ rois, int n, int t,
    float s_w[4][NSAMP], int s_idx[4][NSAMP], int pix_stride /*1 for NCHW, C_ for NHWC*/,
    int fold_batch /*0: no batch in idx; 1: fold b into idx*/ , int* s_b)
{
    const float spatial_scale = 0.25f;
    if (t == 0 && s_b) *s_b = (int)rois[n * 6 + 0];
    if (t < NSAMP) {
        const int   b  = (int)rois[n * 6 + 0];
        const float cx = rois[n * 6 + 1] * spatial_scale;
        const float cy = rois[n * 6 + 2] * spatial_scale;
        const float rw = fmaxf(rois[n * 6 + 3] * spatial_scale, 1.0f);
        const float rh = fmaxf(rois[n * 6 + 4] * spatial_scale, 1.0f);
        const float th = rois[n * 6 + 5];
        const float cosv = cosf(th), sinv = sinf(th);

        const float bin_h = rh * (1.0f / OUTHW);
        const float bin_w = rw * (1.0f / OUTHW);
        const int row = t / GRID_S;
        const int col = t % GRID_S;

        const float yy = -rh * 0.5f + ((float)row + 0.5f) * 0.5f * bin_h;
        const float xx = -rw * 0.5f + ((float)col + 0.5f) * 0.5f * bin_w;

        const float y = yy * cosv - xx * sinv + cy;
        const float x = yy * sinv + xx * cosv + cx;

        const bool inside = (y >= -1.0f) && (y <= (float)H_) &&
                            (x >= -1.0f) && (x <= (float)W_);

        const float yc = fmaxf(y, 0.0f);
        const float xc = fmaxf(x, 0.0f);
        const float fy = floorf(yc);
        const float fx = floorf(xc);
        int yl = min((int)fy, H_ - 1);
        int xl = min((int)fx, W_ - 1);
        const int yh = min(yl + 1, H_ - 1);
        const int xh = min(xl + 1, W_ - 1);
        const float ly = (fy >= (float)(H_ - 1)) ? 0.0f : (yc - fy);
        const float lx = (fx >= (float)(W_ - 1)) ? 0.0f : (xc - fx);
        const float hy = 1.0f - ly;
        const float hx = 1.0f - lx;

        const float m = inside ? 0.25f : 0.0f;   // fold inside-mask + 2x2 mean
        s_w[0][t] = hy * hx * m;
        s_w[1][t] = hy * lx * m;
        s_w[2][t] = ly * hx * m;
        s_w[3][t] = ly * lx * m;
        const int bb = fold_batch ? b : 0;
        s_idx[0][t] = ((bb * H_ + yl) * W_ + xl) * pix_stride;
        s_idx[1][t] = ((bb * H_ + yl) * W_ + xh) * pix_stride;
        s_idx[2][t] = ((bb * H_ + yh) * W_ + xl) * pix_stride;
        s_idx[3][t] = ((bb * H_ + yh) * W_ + xh) * pix_stride;
    }
}

// ---------- main kernel, NHWC path: lanes = channels, float4/lane ----------
__global__ __launch_bounds__(256) void roi_main_nhwc(
    const float* __restrict__ featT,
    const float* __restrict__ rois,
    float* __restrict__ out)
{
    const int n = blockIdx.x;
    const int t = threadIdx.x;
    __shared__ float s_w[4][NSAMP];
    __shared__ int   s_idx[4][NSAMP];   // element offset = ((b*H+y)*W+x)*C

    build_table(rois, n, t, s_w, s_idx, C_, 1, nullptr);
    __syncthreads();

    const int lane  = t & 63;
    const int wave  = t >> 6;
    const int cbase = lane * 4;                 // 4 channels per lane
    float* __restrict__ ob = out + (size_t)n * ELEMS;

    for (int bin = wave; bin < OUTHW * OUTHW; bin += 4) {
        const int oy = bin / OUTHW;
        const int ox = bin - oy * OUTHW;
        float ax = 0.f, ay = 0.f, az = 0.f, aw = 0.f;
        #pragma unroll
        for (int j = 0; j < 2; ++j) {
            #pragma unroll
            for (int i = 0; i < 2; ++i) {
                const int s = (oy * 2 + j) * GRID_S + (ox * 2 + i);
                #pragma unroll
                for (int q = 0; q < 4; ++q) {
                    const float w = s_w[q][s];
                    const float4 v = *(const float4*)(featT + s_idx[q][s] + cbase);
                    ax += w * v.x; ay += w * v.y; az += w * v.z; aw += w * v.w;
                }
            }
        }
        float* o = ob + (size_t)cbase * 49 + bin;  // out[n][cbase+k][oy][ox]
        o[0]   = ax;
        o[49]  = ay;
        o[98]  = az;
        o[147] = aw;
    }
}

// ---------- fallback (R0 kernel, NCHW, known-correct) ----------
__global__ __launch_bounds__(256) void roi_main_nchw(
    const float* __restrict__ feat,
    const float* __restrict__ rois,
    float* __restrict__ out)
{
    const int n = blockIdx.x;
    const int t = threadIdx.x;
    __shared__ float s_w[4][NSAMP];
    __shared__ int   s_idx[4][NSAMP];
    __shared__ int   s_b;

    build_table(rois, n, t, s_w, s_idx, 1, 0, &s_b);
    __syncthreads();

    const float* __restrict__ fb = feat + (size_t)s_b * (size_t)(C_ * H_ * W_);
    float* __restrict__ ob = out + (size_t)n * (size_t)ELEMS;

    for (int e = t; e < ELEMS; e += 256) {
        const int c   = e / 49;
        const int bin = e - c * 49;
        const int oy  = bin / 7;
        const int ox  = bin - oy * 7;
        const float* __restrict__ fc = fb + c * (H_ * W_);
        float acc = 0.0f;
        #pragma unroll
        for (int j = 0; j < 2; ++j) {
            #pragma unroll
            for (int i = 0; i < 2; ++i) {
                const int s = (oy * 2 + j) * GRID_S + (ox * 2 + i);
                acc += s_w[0][s] * fc[s_idx[0][s]];
                acc += s_w[1][s] * fc[s_idx[1][s]];
                acc += s_w[2][s] * fc[s_idx[2][s]];
                acc += s_w[3][s] * fc[s_idx[3][s]];
            }
        }
        ob[e] = acc;
    }
}

extern "C" void kernel_launch(void* const* d_in, const int* in_sizes, int n_in,
                              void* d_out, int out_size, void* d_ws, size_t ws_size,
                              hipStream_t stream) {
    const float* feat = (const float*)d_in[0];
    const float* rois = (const float*)d_in[1];
    float* out = (float*)d_out;
    const int N = in_sizes[1] / 6;  // 1000

    const size_t need = (size_t)B_ * H_ * W_ * C_ * sizeof(float); // 163.84 MB
    if (ws_size >= need) {
        float* featT = (float*)d_ws;
        dim3 tg((W_ + 15) / 16, H_, B_);
        transpose_kernel<<<tg, 256, 0, stream>>>(feat, featT);
        roi_main_nhwc<<<N, 256, 0, stream>>>(featT, rois, out);
    } else {
        roi_main_nchw<<<N, 256, 0, stream>>>(feat, rois, out);
    }
}

// Round 3
// 185.163 us; speedup vs baseline: 6.6774x; 1.8672x over previous
//
#include <hip/hip_runtime.h>
#include <hip/hip_fp16.h>

// RoIAlignRotated on MI355X — R2.
// 1) feat NCHW f32 -> featT NHWC fp16 via LDS-tiled transpose (coalesced both
//    sides; fp16 halves gather traffic, error ~3e-3 << 4.5e-2 threshold).
// 2) main kernel: lanes = channels (4 ch * fp16 = 8B/lane, 512B/wave/corner,
//    fully coalesced gathers), per-roi sample table in LDS.
// 3) outputs staged in swizzled LDS buffer, final stores fully coalesced
//    (fixes R1's 287MB-vs-50MB write amplification).

#define B_ 2
#define C_ 256
#define H_ 200
#define W_ 200
#define OUTHW 7
#define GRID_S 14          // OUTHW * sampling_ratio(2)
#define NSAMP 196          // 14*14
#define ELEMS (C_ * OUTHW * OUTHW)  // 12544

// ---------- NCHW f32 -> NHWC fp16, LDS-tiled ----------
__global__ __launch_bounds__(256) void transpose_h_kernel(
    const float* __restrict__ feat, __half* __restrict__ featT)
{
    __shared__ float tile[64][65];   // [c_local][x_local], stride 65 -> 2-way free
    const int x0   = blockIdx.x * 64;
    const int c0   = blockIdx.y * 64;
    const int yb   = blockIdx.z;     // b*H_ + y
    const int y    = yb % H_;
    const int b    = yb / H_;
    const int t    = threadIdx.x;
    const int lane = t & 63;
    const int grp  = t >> 6;         // 0..3
    const int nx   = min(64, W_ - x0);

    // read: lanes along x -> 256B coalesced per instruction
    if (lane < nx) {
        #pragma unroll
        for (int i = 0; i < 16; ++i) {
            const int cl = grp * 16 + i;
            tile[cl][lane] =
                feat[((size_t)(b * C_ + c0 + cl) * H_ + y) * W_ + x0 + lane];
        }
    }
    __syncthreads();

    // write: lanes along c -> 128B contiguous fp16 store per instruction
    for (int i = grp; i < nx; i += 4) {
        const float v = tile[lane][i];   // stride-65 across lanes: conflict-free
        featT[((size_t)(b * H_ + y) * W_ + x0 + i) * C_ + c0 + lane] =
            __float2half(v);
    }
}

// ---------- per-roi sample table (channel-independent) ----------
__device__ __forceinline__ void build_table(
    const float* __restrict__ rois, int n, int t,
    float s_w[4][NSAMP], int s_idx[4][NSAMP], int pix_stride, int fold_batch,
    int* s_b)
{
    const float spatial_scale = 0.25f;
    if (t == 0 && s_b) *s_b = (int)rois[n * 6 + 0];
    if (t < NSAMP) {
        const int   b  = (int)rois[n * 6 + 0];
        const float cx = rois[n * 6 + 1] * spatial_scale;
        const float cy = rois[n * 6 + 2] * spatial_scale;
        const float rw = fmaxf(rois[n * 6 + 3] * spatial_scale, 1.0f);
        const float rh = fmaxf(rois[n * 6 + 4] * spatial_scale, 1.0f);
        const float th = rois[n * 6 + 5];
        const float cosv = cosf(th), sinv = sinf(th);

        const float bin_h = rh * (1.0f / OUTHW);
        const float bin_w = rw * (1.0f / OUTHW);
        const int row = t / GRID_S;
        const int col = t % GRID_S;

        const float yy = -rh * 0.5f + ((float)row + 0.5f) * 0.5f * bin_h;
        const float xx = -rw * 0.5f + ((float)col + 0.5f) * 0.5f * bin_w;

        const float y = yy * cosv - xx * sinv + cy;
        const float x = yy * sinv + xx * cosv + cx;

        const bool inside = (y >= -1.0f) && (y <= (float)H_) &&
                            (x >= -1.0f) && (x <= (float)W_);

        const float yc = fmaxf(y, 0.0f);
        const float xc = fmaxf(x, 0.0f);
        const float fy = floorf(yc);
        const float fx = floorf(xc);
        int yl = min((int)fy, H_ - 1);
        int xl = min((int)fx, W_ - 1);
        const int yh = min(yl + 1, H_ - 1);
        const int xh = min(xl + 1, W_ - 1);
        const float ly = (fy >= (float)(H_ - 1)) ? 0.0f : (yc - fy);
        const float lx = (fx >= (float)(W_ - 1)) ? 0.0f : (xc - fx);
        const float hy = 1.0f - ly;
        const float hx = 1.0f - lx;

        const float m = inside ? 0.25f : 0.0f;   // fold inside-mask + 2x2 mean
        s_w[0][t] = hy * hx * m;
        s_w[1][t] = hy * lx * m;
        s_w[2][t] = ly * hx * m;
        s_w[3][t] = ly * lx * m;
        const int bb = fold_batch ? b : 0;
        s_idx[0][t] = ((bb * H_ + yl) * W_ + xl) * pix_stride;
        s_idx[1][t] = ((bb * H_ + yl) * W_ + xh) * pix_stride;
        s_idx[2][t] = ((bb * H_ + yh) * W_ + xl) * pix_stride;
        s_idx[3][t] = ((bb * H_ + yh) * W_ + xh) * pix_stride;
    }
}

// ---------- main kernel: NHWC fp16 gathers + LDS-staged coalesced output ----
__global__ __launch_bounds__(256) void roi_main_nhwc_h(
    const __half* __restrict__ featT,
    const float* __restrict__ rois,
    float* __restrict__ out)
{
    __shared__ float s_w[4][NSAMP];
    __shared__ int   s_idx[4][NSAMP];
    __shared__ float s_out[49][257];   // [bin][swizzled c], stride 257

    const int n = blockIdx.x;
    const int t = threadIdx.x;
    build_table(rois, n, t, s_w, s_idx, C_, 1, nullptr);
    __syncthreads();

    const int lane  = t & 63;
    const int wave  = t >> 6;
    const int cbase = lane * 4;        // 4 channels per lane

    for (int bin = wave; bin < OUTHW * OUTHW; bin += 4) {
        const int oy = bin / OUTHW;
        const int ox = bin - oy * OUTHW;
        float a0 = 0.f, a1 = 0.f, a2 = 0.f, a3 = 0.f;
        #pragma unroll
        for (int j = 0; j < 2; ++j) {
            #pragma unroll
            for (int i = 0; i < 2; ++i) {
                const int s = (oy * 2 + j) * GRID_S + (ox * 2 + i);
                #pragma unroll
                for (int q = 0; q < 4; ++q) {
                    const float w = s_w[q][s];
                    const __half2* p =
                        (const __half2*)(featT + s_idx[q][s] + cbase);
                    const float2 fa = __half22float2(p[0]);
                    const float2 fb = __half22float2(p[1]);
                    a0 += w * fa.x; a1 += w * fa.y;
                    a2 += w * fb.x; a3 += w * fb.y;
                }
            }
        }
        // swizzle: channel c=cbase+k stored at col k*64+lane -> each store is
        // stride-1 across lanes: conflict-free b32 writes
        s_out[bin][0 * 64 + lane] = a0;
        s_out[bin][1 * 64 + lane] = a1;
        s_out[bin][2 * 64 + lane] = a2;
        s_out[bin][3 * 64 + lane] = a3;
    }
    __syncthreads();

    // coalesced final stores: 1KB per wave-instruction
    float* __restrict__ ob = out + (size_t)n * ELEMS;
    for (int k = 0; k < 49; ++k) {
        const int e   = t + k * 256;
        const int c   = e / 49;
        const int bin = e - c * 49;
        // lanes: consecutive bin at ~fixed c -> LDS stride 257: conflict-free
        ob[e] = s_out[bin][(c & 3) * 64 + (c >> 2)];
    }
}

// ---------- fallback (known-correct NCHW path, no workspace) ----------
__global__ __launch_bounds__(256) void roi_main_nchw(
    const float* __restrict__ feat,
    const float* __restrict__ rois,
    float* __restrict__ out)
{
    const int n = blockIdx.x;
    const int t = threadIdx.x;
    __shared__ float s_w[4][NSAMP];
    __shared__ int   s_idx[4][NSAMP];
    __shared__ int   s_b;

    build_table(rois, n, t, s_w, s_idx, 1, 0, &s_b);
    __syncthreads();

    const float* __restrict__ fb = feat + (size_t)s_b * (size_t)(C_ * H_ * W_);
    float* __restrict__ ob = out + (size_t)n * (size_t)ELEMS;

    for (int e = t; e < ELEMS; e += 256) {
        const int c   = e / 49;
        const int bin = e - c * 49;
        const int oy  = bin / 7;
        const int ox  = bin - oy * 7;
        const float* __restrict__ fc = fb + c * (H_ * W_);
        float acc = 0.0f;
        #pragma unroll
        for (int j = 0; j < 2; ++j) {
            #pragma unroll
            for (int i = 0; i < 2; ++i) {
                const int s = (oy * 2 + j) * GRID_S + (ox * 2 + i);
                acc += s_w[0][s] * fc[s_idx[0][s]];
                acc += s_w[1][s] * fc[s_idx[1][s]];
                acc += s_w[2][s] * fc[s_idx[2][s]];
                acc += s_w[3][s] * fc[s_idx[3][s]];
            }
        }
        ob[e] = acc;
    }
}

extern "C" void kernel_launch(void* const* d_in, const int* in_sizes, int n_in,
                              void* d_out, int out_size, void* d_ws, size_t ws_size,
                              hipStream_t stream) {
    const float* feat = (const float*)d_in[0];
    const float* rois = (const float*)d_in[1];
    float* out = (float*)d_out;
    const int N = in_sizes[1] / 6;  // 1000

    const size_t need = (size_t)B_ * H_ * W_ * C_ * sizeof(__half); // 41 MB
    if (ws_size >= need) {
        __half* featT = (__half*)d_ws;
        dim3 tg((W_ + 63) / 64, C_ / 64, H_ * B_);
        transpose_h_kernel<<<tg, 256, 0, stream>>>(feat, featT);
        roi_main_nhwc_h<<<N, 256, 0, stream>>>(featT, rois, out);
    } else {
        roi_main_nchw<<<N, 256, 0, stream>>>(feat, rois, out);
    }
}